// Round 13
// baseline (405.546 us; speedup 1.0000x reference)
//
#include <hip/hip_runtime.h>
#include <math.h>

#define D_FEAT 12544
#define NC 1000
#define RMAX 40        // rows per k4 tier
#define S64 64         // global D slices
#define DSL 196        // D_FEAT / S64
#define NIT4 (DSL/4)   // 49 d4 iterations

// ---------------- K1: conv1(1->32,3x3,VALID)+ReLU+maxpool2 -> h1[128,31,31,32]
__global__ __launch_bounds__(256) void k1_conv1(
    const float* __restrict__ x, const float* __restrict__ w,
    const float* __restrict__ bias, float* __restrict__ h1,
    int* __restrict__ cnt)
{
    // zero routing counters (stream-ordered before k3)
    if (blockIdx.x == 0 && threadIdx.x < 8) cnt[threadIdx.x] = 0;

    int co  = threadIdx.x & 31;
    int pxi = threadIdx.x >> 5;          // 0..7
    int blk = blockIdx.x;
    int pxg = blk & 3;
    int py  = (blk >> 2) % 31;
    int b   = blk / (31 * 4);
    int px  = pxg * 8 + pxi;
    if (px >= 31) return;

    float wr[9];
#pragma unroll
    for (int t = 0; t < 9; ++t) wr[t] = w[t * 32 + co];
    float bb = bias[co];

    float in[4][4];
    const float* xb = x + ((size_t)(b * 64 + 2 * py) * 64 + 2 * px);
#pragma unroll
    for (int r = 0; r < 4; ++r)
#pragma unroll
        for (int c = 0; c < 4; ++c)
            in[r][c] = xb[r * 64 + c];

    float a00 = 0.f, a01 = 0.f, a10 = 0.f, a11 = 0.f;
#pragma unroll
    for (int ky = 0; ky < 3; ++ky)
#pragma unroll
        for (int kx = 0; kx < 3; ++kx) {
            float wv = wr[ky * 3 + kx];
            a00 = fmaf(in[ky][kx],     wv, a00);
            a01 = fmaf(in[ky][kx + 1], wv, a01);
            a10 = fmaf(in[ky + 1][kx], wv, a10);
            a11 = fmaf(in[ky + 1][kx + 1], wv, a11);
        }
    a00 = fmaxf(a00 + bb, 0.f);
    a01 = fmaxf(a01 + bb, 0.f);
    a10 = fmaxf(a10 + bb, 0.f);
    a11 = fmaxf(a11 + bb, 0.f);
    float v = fmaxf(fmaxf(a00, a01), fmaxf(a10, a11));
    h1[((size_t)(b * 31 + py) * 31 + px) * 32 + co] = v;
}

// ---------------- K2: conv2(32->64,3x3,VALID)+ReLU+maxpool2 -> h[128,14,14,64]
__global__ __launch_bounds__(448) void k2_conv2(
    const float* __restrict__ h1, const float* __restrict__ w2,
    const float* __restrict__ b2, float* __restrict__ h)
{
    __shared__ float wl[9 * 32 * 32];    // [tap][ci][co_local] 36864 B

    int co  = threadIdx.x & 31;
    int px  = threadIdx.x >> 5;          // 0..13
    int blk = blockIdx.x;
    int cob = blk & 1;
    int py  = (blk >> 1) % 14;
    int b   = blk / 28;

    for (int i = threadIdx.x; i < 9 * 32 * 32; i += 448) {
        int tapci = i >> 5;
        int col   = i & 31;
        wl[i] = w2[tapci * 64 + cob * 32 + col];
    }
    __syncthreads();

    float acc00 = 0.f, acc01 = 0.f, acc10 = 0.f, acc11 = 0.f;
    const float* base = h1 + ((size_t)(b * 31 + 2 * py) * 31 + 2 * px) * 32;

    for (int q = 0; q < 8; ++q) {
        float4 in4[4][4];
#pragma unroll
        for (int r = 0; r < 4; ++r)
#pragma unroll
            for (int c = 0; c < 4; ++c)
                in4[r][c] = *(const float4*)(base + (r * 31 + c) * 32 + q * 4);

#pragma unroll
        for (int ky = 0; ky < 3; ++ky)
#pragma unroll
            for (int kx = 0; kx < 3; ++kx) {
                int tap = ky * 3 + kx;
                const float* wp = &wl[(tap * 32 + q * 4) * 32 + co];
                float w0 = wp[0];
                float w1 = wp[32];
                float w2v = wp[64];
                float w3 = wp[96];
                acc00 = fmaf(in4[ky][kx].x, w0, acc00);
                acc00 = fmaf(in4[ky][kx].y, w1, acc00);
                acc00 = fmaf(in4[ky][kx].z, w2v, acc00);
                acc00 = fmaf(in4[ky][kx].w, w3, acc00);
                acc01 = fmaf(in4[ky][kx + 1].x, w0, acc01);
                acc01 = fmaf(in4[ky][kx + 1].y, w1, acc01);
                acc01 = fmaf(in4[ky][kx + 1].z, w2v, acc01);
                acc01 = fmaf(in4[ky][kx + 1].w, w3, acc01);
                acc10 = fmaf(in4[ky + 1][kx].x, w0, acc10);
                acc10 = fmaf(in4[ky + 1][kx].y, w1, acc10);
                acc10 = fmaf(in4[ky + 1][kx].z, w2v, acc10);
                acc10 = fmaf(in4[ky + 1][kx].w, w3, acc10);
                acc11 = fmaf(in4[ky + 1][kx + 1].x, w0, acc11);
                acc11 = fmaf(in4[ky + 1][kx + 1].y, w1, acc11);
                acc11 = fmaf(in4[ky + 1][kx + 1].z, w2v, acc11);
                acc11 = fmaf(in4[ky + 1][kx + 1].w, w3, acc11);
            }
    }

    float bb = b2[cob * 32 + co];
    acc00 = fmaxf(acc00 + bb, 0.f);
    acc01 = fmaxf(acc01 + bb, 0.f);
    acc10 = fmaxf(acc10 + bb, 0.f);
    acc11 = fmaxf(acc11 + bb, 0.f);
    float v = fmaxf(fmaxf(acc00, acc01), fmaxf(acc10, acc11));
    h[(size_t)b * D_FEAT + (py * 14 + px) * 64 + cob * 32 + co] = v;
}

// ---------------- K3: gate logits + softmax + top2 + routing lists (with k index)
__global__ __launch_bounds__(256) void k3_gate(
    const float* __restrict__ h, const float* __restrict__ gw,
    const float* __restrict__ gb, int* __restrict__ cnt,
    int* __restrict__ rowIdx, float* __restrict__ rowW,
    int* __restrict__ rowK, int* __restrict__ top2e, float* __restrict__ top2w)
{
    int b = blockIdx.x;
    int tid = threadIdx.x;
    float acc[8];
#pragma unroll
    for (int e = 0; e < 8; ++e) acc[e] = 0.f;

    const float* hb = h + (size_t)b * D_FEAT;
    for (int d = tid; d < D_FEAT; d += 256) {
        float hv = hb[d];
        float4 g0 = *(const float4*)(gw + (size_t)d * 8);
        float4 g1 = *(const float4*)(gw + (size_t)d * 8 + 4);
        acc[0] = fmaf(hv, g0.x, acc[0]);
        acc[1] = fmaf(hv, g0.y, acc[1]);
        acc[2] = fmaf(hv, g0.z, acc[2]);
        acc[3] = fmaf(hv, g0.w, acc[3]);
        acc[4] = fmaf(hv, g1.x, acc[4]);
        acc[5] = fmaf(hv, g1.y, acc[5]);
        acc[6] = fmaf(hv, g1.z, acc[6]);
        acc[7] = fmaf(hv, g1.w, acc[7]);
    }

#pragma unroll
    for (int e = 0; e < 8; ++e) {
        float v = acc[e];
        v += __shfl_down(v, 32, 64);
        v += __shfl_down(v, 16, 64);
        v += __shfl_down(v, 8, 64);
        v += __shfl_down(v, 4, 64);
        v += __shfl_down(v, 2, 64);
        v += __shfl_down(v, 1, 64);
        acc[e] = v;
    }

    __shared__ float sm[4][8];
    int wid = tid >> 6, ln = tid & 63;
    if (ln == 0) {
#pragma unroll
        for (int e = 0; e < 8; ++e) sm[wid][e] = acc[e];
    }
    __syncthreads();

    if (tid == 0) {
        float lg[8], p[8];
        float m = -1e30f;
#pragma unroll
        for (int e = 0; e < 8; ++e) {
            lg[e] = sm[0][e] + sm[1][e] + sm[2][e] + sm[3][e] + gb[e];
            m = fmaxf(m, lg[e]);
        }
        float s = 0.f;
#pragma unroll
        for (int e = 0; e < 8; ++e) { p[e] = expf(lg[e] - m); s += p[e]; }
        float inv = 1.f / s;
#pragma unroll
        for (int e = 0; e < 8; ++e) p[e] *= inv;

        int i0 = 0;
#pragma unroll
        for (int e = 1; e < 8; ++e) if (p[e] > p[i0]) i0 = e;
        int i1 = (i0 == 0) ? 1 : 0;
#pragma unroll
        for (int e = 0; e < 8; ++e) if (e != i0 && p[e] > p[i1]) i1 = e;

        int pos0 = atomicAdd(&cnt[i0], 1);
        rowIdx[i0 * 128 + pos0] = b;
        rowW[i0 * 128 + pos0] = p[i0];
        rowK[i0 * 128 + pos0] = 0;
        int pos1 = atomicAdd(&cnt[i1], 1);
        rowIdx[i1 * 128 + pos1] = b;
        rowW[i1 * 128 + pos1] = p[i1];
        rowK[i1 * 128 + pos1] = 1;

        top2e[b * 2]     = i0;
        top2e[b * 2 + 1] = i1;
        top2w[b * 2]     = p[i0];
        top2w[b * 2 + 1] = p[i1];
    }
}

// float2-column FMA: acc(2 cols) += hv(4 dims) dot W rows
#define FMA_ROW2(A, HV, W0, W1, W2, W3)                         \
    do {                                                        \
        (A).x = fmaf((HV).x, (W0).x, (A).x);                    \
        (A).x = fmaf((HV).y, (W1).x, (A).x);                    \
        (A).x = fmaf((HV).z, (W2).x, (A).x);                    \
        (A).x = fmaf((HV).w, (W3).x, (A).x);                    \
        (A).y = fmaf((HV).x, (W0).y, (A).y);                    \
        (A).y = fmaf((HV).y, (W1).y, (A).y);                    \
        (A).y = fmaf((HV).z, (W2).y, (A).y);                    \
        (A).y = fmaf((HV).w, (W3).y, (A).y);                    \
    } while (0)

// ---------------- K4: grouped expert GEMM, W read EXACTLY ONCE per (s,e) tier
// grid = rc(4, HIGH bits, sparse beyond n>40) x e(8) x s(64, LOW bits -> XCDs).
// block 512 thr: 500 active x 2 cols (float2), all RMAX=40 rows in registers.
// L2 amplification 1x (was 4.5x); uniform 40-row FMA -> no imbalance tail.
__global__ __launch_bounds__(512, 4) void k4_expert(
    const float* __restrict__ h, const float* __restrict__ ew,
    const int* __restrict__ cnt, const int* __restrict__ rowIdx,
    const float* __restrict__ rowW, const int* __restrict__ rowK,
    float* __restrict__ part)
{
    __shared__ float h_lds[RMAX * DSL];         // 31360 B
    __shared__ int   roff_s[RMAX];

    int tid  = threadIdx.x;
    int bid  = blockIdx.x;
    int rc   = bid >> 9;                 // 0..3 (tiers of 40 rows)
    int base = bid & 511;
    int s    = base & 63;                // LOW bits: uniform across XCDs
    int e    = base >> 6;

    int n = cnt[e];
    int rbase = rc * RMAX;
    if (rbase >= n) return;
    int nrows = n - rbase; if (nrows > RMAX) nrows = RMAX;

    if (tid < RMAX) {
        roff_s[tid] = (tid < nrows) ? rowIdx[e * 128 + rbase + tid] * D_FEAT : -1;
    }
    __syncthreads();

    int dbase = s * DSL;
    // stage h rows [RMAX x DSL] into LDS (zeros for invalid rows)
    for (int i = tid; i < RMAX * NIT4; i += 512) {
        int r = i / NIT4;
        int q = i - r * NIT4;
        int ro = roff_s[r];
        float4 v = make_float4(0.f, 0.f, 0.f, 0.f);
        if (ro >= 0) v = *(const float4*)(h + ro + dbase + q * 4);
        *(float4*)&h_lds[r * DSL + q * 4] = v;
    }
    __syncthreads();

    if (tid < 500) {                      // 500 active threads, 2 cols each
        const float* wp = ew + ((size_t)e * D_FEAT + dbase) * NC + tid * 2;

        float2 acc[RMAX];
#pragma unroll
        for (int r = 0; r < RMAX; ++r) acc[r] = make_float2(0.f, 0.f);

        float2 wA0 = *(const float2*)(wp);
        float2 wA1 = *(const float2*)(wp + (size_t)NC);
        float2 wA2 = *(const float2*)(wp + (size_t)2 * NC);
        float2 wA3 = *(const float2*)(wp + (size_t)3 * NC);

        for (int it = 0; it < NIT4; ++it) {
            const float* np = wp + (size_t)4 * NC;
            float2 wB0, wB1, wB2, wB3;
            if (it < NIT4 - 1) {
                wB0 = *(const float2*)(np);
                wB1 = *(const float2*)(np + (size_t)NC);
                wB2 = *(const float2*)(np + (size_t)2 * NC);
                wB3 = *(const float2*)(np + (size_t)3 * NC);
            }
            const float* hp = &h_lds[it * 4];
#pragma unroll
            for (int r = 0; r < RMAX; ++r) {     // unconditional: pad rows zero
                float4 hv = *(const float4*)(hp + r * DSL);
                FMA_ROW2(acc[r], hv, wA0, wA1, wA2, wA3);
            }
            wp = np;
            wA0 = wB0; wA1 = wB1; wA2 = wB2; wA3 = wB3;
        }

#pragma unroll
        for (int r = 0; r < RMAX; ++r) {
            if (r < nrows) {
                int pos = e * 128 + rbase + r;
                float wgt = rowW[pos];
                int ri = rowIdx[pos];
                int kk = rowK[pos];
                float2 o = make_float2(wgt * acc[r].x, wgt * acc[r].y);
                *(float2*)&part[(((size_t)s * 128 + ri) * 2 + kk) * NC + tid * 2] = o;
            }
        }
    }
}

// ---------------- K5: sum partials + weighted expert bias, row softmax
__global__ __launch_bounds__(256) void k5_softmax(
    const float* __restrict__ part, const float* __restrict__ eb,
    const int* __restrict__ top2e, const float* __restrict__ top2w,
    float* __restrict__ out)
{
    int b = blockIdx.x;
    int tid = threadIdx.x;
    __shared__ float red[4];

    int e0 = top2e[b * 2], e1 = top2e[b * 2 + 1];
    float tw0 = top2w[b * 2], tw1 = top2w[b * 2 + 1];

    bool act = (tid < 250);
    int c0 = tid * 4;
    float4 v = make_float4(-1e30f, -1e30f, -1e30f, -1e30f);
    if (act) {
        float4 a = make_float4(0.f, 0.f, 0.f, 0.f);
        for (int s = 0; s < S64; ++s) {
            const float* p0 = part + (((size_t)s * 128 + b) * 2) * NC + c0;
            float4 q0 = *(const float4*)p0;
            float4 q1 = *(const float4*)(p0 + NC);
            a.x += q0.x + q1.x;
            a.y += q0.y + q1.y;
            a.z += q0.z + q1.z;
            a.w += q0.w + q1.w;
        }
        float4 b0 = *(const float4*)(eb + e0 * NC + c0);
        float4 b1 = *(const float4*)(eb + e1 * NC + c0);
        v.x = a.x + tw0 * b0.x + tw1 * b1.x;
        v.y = a.y + tw0 * b0.y + tw1 * b1.y;
        v.z = a.z + tw0 * b0.z + tw1 * b1.z;
        v.w = a.w + tw0 * b0.w + tw1 * b1.w;
    }

    float m = fmaxf(fmaxf(v.x, v.y), fmaxf(v.z, v.w));
#pragma unroll
    for (int off = 32; off >= 1; off >>= 1)
        m = fmaxf(m, __shfl_xor(m, off, 64));
    int wid = tid >> 6, ln = tid & 63;
    if (ln == 0) red[wid] = m;
    __syncthreads();
    m = fmaxf(fmaxf(red[0], red[1]), fmaxf(red[2], red[3]));
    __syncthreads();

    float ex, ey, ez, ew2;
    ex = act ? expf(v.x - m) : 0.f;
    ey = act ? expf(v.y - m) : 0.f;
    ez = act ? expf(v.z - m) : 0.f;
    ew2 = act ? expf(v.w - m) : 0.f;
    float ssum = ex + ey + ez + ew2;
#pragma unroll
    for (int off = 32; off >= 1; off >>= 1)
        ssum += __shfl_xor(ssum, off, 64);
    if (ln == 0) red[wid] = ssum;
    __syncthreads();
    ssum = red[0] + red[1] + red[2] + red[3];
    float inv = 1.f / ssum;

    if (act) {
        float4 o = make_float4(ex * inv, ey * inv, ez * inv, ew2 * inv);
        *(float4*)&out[(size_t)b * NC + c0] = o;
    }
}

extern "C" void kernel_launch(void* const* d_in, const int* in_sizes, int n_in,
                              void* d_out, int out_size, void* d_ws, size_t ws_size,
                              hipStream_t stream) {
    const float* x   = (const float*)d_in[0];
    const float* c1w = (const float*)d_in[1];
    const float* c1b = (const float*)d_in[2];
    const float* c2w = (const float*)d_in[3];
    const float* c2b = (const float*)d_in[4];
    const float* gw  = (const float*)d_in[5];
    const float* gb  = (const float*)d_in[6];
    const float* ew  = (const float*)d_in[7];
    const float* eb  = (const float*)d_in[8];
    float* out = (float*)d_out;

    char* ws = (char*)d_ws;
    // layout (part overlays dead h1 region):
    //   smalls:  0 .. 16384
    //   h:       16384 .. 6438912                  (6,422,528 B)
    //   h1:      6438912 .. 22183936               (15,745,024 B, dead after k2)
    //   part:    6438912 .. 71974912               (65,536,000 B, alive k4..k5)
    int*   cnt    = (int*)  (ws + 0);        //    32 B
    int*   rowIdx = (int*)  (ws + 64);       //  4096 B
    float* rowW   = (float*)(ws + 4160);     //  4096 B
    int*   rowK   = (int*)  (ws + 8256);     //  4096 B
    int*   top2e  = (int*)  (ws + 12352);    //  1024 B
    float* top2w  = (float*)(ws + 13376);    //  1024 B
    float* h      = (float*)(ws + 16384);
    float* h1     = (float*)(ws + 6438912);
    float* part   = (float*)(ws + 6438912);

    k1_conv1<<<128 * 31 * 4, 256, 0, stream>>>(x, c1w, c1b, h1, cnt);
    k2_conv2<<<128 * 14 * 2, 448, 0, stream>>>(h1, c2w, c2b, h);
    k3_gate<<<128, 256, 0, stream>>>(h, gw, gb, cnt, rowIdx, rowW, rowK, top2e, top2w);
    k4_expert<<<4 * 8 * 64, 512, 0, stream>>>(h, ew, cnt, rowIdx, rowW, rowK, part);
    k5_softmax<<<128, 256, 0, stream>>>(part, eb, top2e, top2w, out);
}

// Round 14
// 393.696 us; speedup vs baseline: 1.0301x; 1.0301x over previous
//
#include <hip/hip_runtime.h>
#include <math.h>

#define D_FEAT 12544
#define NC 1000
#define RMAX 32        // rows per k4 tier
#define S64 64         // global D slices
#define DSL 196        // D_FEAT / S64
#define NIT4 (DSL/4)   // 49 d4 iterations

// ---------------- K1: conv1(1->32,3x3,VALID)+ReLU+maxpool2 -> h1[128,31,31,32]
__global__ __launch_bounds__(256) void k1_conv1(
    const float* __restrict__ x, const float* __restrict__ w,
    const float* __restrict__ bias, float* __restrict__ h1,
    int* __restrict__ cnt)
{
    // zero routing counters (stream-ordered before k3)
    if (blockIdx.x == 0 && threadIdx.x < 8) cnt[threadIdx.x] = 0;

    int co  = threadIdx.x & 31;
    int pxi = threadIdx.x >> 5;          // 0..7
    int blk = blockIdx.x;
    int pxg = blk & 3;
    int py  = (blk >> 2) % 31;
    int b   = blk / (31 * 4);
    int px  = pxg * 8 + pxi;
    if (px >= 31) return;

    float wr[9];
#pragma unroll
    for (int t = 0; t < 9; ++t) wr[t] = w[t * 32 + co];
    float bb = bias[co];

    float in[4][4];
    const float* xb = x + ((size_t)(b * 64 + 2 * py) * 64 + 2 * px);
#pragma unroll
    for (int r = 0; r < 4; ++r)
#pragma unroll
        for (int c = 0; c < 4; ++c)
            in[r][c] = xb[r * 64 + c];

    float a00 = 0.f, a01 = 0.f, a10 = 0.f, a11 = 0.f;
#pragma unroll
    for (int ky = 0; ky < 3; ++ky)
#pragma unroll
        for (int kx = 0; kx < 3; ++kx) {
            float wv = wr[ky * 3 + kx];
            a00 = fmaf(in[ky][kx],     wv, a00);
            a01 = fmaf(in[ky][kx + 1], wv, a01);
            a10 = fmaf(in[ky + 1][kx], wv, a10);
            a11 = fmaf(in[ky + 1][kx + 1], wv, a11);
        }
    a00 = fmaxf(a00 + bb, 0.f);
    a01 = fmaxf(a01 + bb, 0.f);
    a10 = fmaxf(a10 + bb, 0.f);
    a11 = fmaxf(a11 + bb, 0.f);
    float v = fmaxf(fmaxf(a00, a01), fmaxf(a10, a11));
    h1[((size_t)(b * 31 + py) * 31 + px) * 32 + co] = v;
}

// ---------------- K2: conv2(32->64,3x3,VALID)+ReLU+maxpool2 -> h[128,14,14,64]
__global__ __launch_bounds__(448) void k2_conv2(
    const float* __restrict__ h1, const float* __restrict__ w2,
    const float* __restrict__ b2, float* __restrict__ h)
{
    __shared__ float wl[9 * 32 * 32];    // [tap][ci][co_local] 36864 B

    int co  = threadIdx.x & 31;
    int px  = threadIdx.x >> 5;          // 0..13
    int blk = blockIdx.x;
    int cob = blk & 1;
    int py  = (blk >> 1) % 14;
    int b   = blk / 28;

    for (int i = threadIdx.x; i < 9 * 32 * 32; i += 448) {
        int tapci = i >> 5;
        int col   = i & 31;
        wl[i] = w2[tapci * 64 + cob * 32 + col];
    }
    __syncthreads();

    float acc00 = 0.f, acc01 = 0.f, acc10 = 0.f, acc11 = 0.f;
    const float* base = h1 + ((size_t)(b * 31 + 2 * py) * 31 + 2 * px) * 32;

    for (int q = 0; q < 8; ++q) {
        float4 in4[4][4];
#pragma unroll
        for (int r = 0; r < 4; ++r)
#pragma unroll
            for (int c = 0; c < 4; ++c)
                in4[r][c] = *(const float4*)(base + (r * 31 + c) * 32 + q * 4);

#pragma unroll
        for (int ky = 0; ky < 3; ++ky)
#pragma unroll
            for (int kx = 0; kx < 3; ++kx) {
                int tap = ky * 3 + kx;
                const float* wp = &wl[(tap * 32 + q * 4) * 32 + co];
                float w0 = wp[0];
                float w1 = wp[32];
                float w2v = wp[64];
                float w3 = wp[96];
                acc00 = fmaf(in4[ky][kx].x, w0, acc00);
                acc00 = fmaf(in4[ky][kx].y, w1, acc00);
                acc00 = fmaf(in4[ky][kx].z, w2v, acc00);
                acc00 = fmaf(in4[ky][kx].w, w3, acc00);
                acc01 = fmaf(in4[ky][kx + 1].x, w0, acc01);
                acc01 = fmaf(in4[ky][kx + 1].y, w1, acc01);
                acc01 = fmaf(in4[ky][kx + 1].z, w2v, acc01);
                acc01 = fmaf(in4[ky][kx + 1].w, w3, acc01);
                acc10 = fmaf(in4[ky + 1][kx].x, w0, acc10);
                acc10 = fmaf(in4[ky + 1][kx].y, w1, acc10);
                acc10 = fmaf(in4[ky + 1][kx].z, w2v, acc10);
                acc10 = fmaf(in4[ky + 1][kx].w, w3, acc10);
                acc11 = fmaf(in4[ky + 1][kx + 1].x, w0, acc11);
                acc11 = fmaf(in4[ky + 1][kx + 1].y, w1, acc11);
                acc11 = fmaf(in4[ky + 1][kx + 1].z, w2v, acc11);
                acc11 = fmaf(in4[ky + 1][kx + 1].w, w3, acc11);
            }
    }

    float bb = b2[cob * 32 + co];
    acc00 = fmaxf(acc00 + bb, 0.f);
    acc01 = fmaxf(acc01 + bb, 0.f);
    acc10 = fmaxf(acc10 + bb, 0.f);
    acc11 = fmaxf(acc11 + bb, 0.f);
    float v = fmaxf(fmaxf(acc00, acc01), fmaxf(acc10, acc11));
    h[(size_t)b * D_FEAT + (py * 14 + px) * 64 + cob * 32 + co] = v;
}

// ---------------- K3: gate logits + softmax + top2 + routing lists (with k index)
__global__ __launch_bounds__(256) void k3_gate(
    const float* __restrict__ h, const float* __restrict__ gw,
    const float* __restrict__ gb, int* __restrict__ cnt,
    int* __restrict__ rowIdx, float* __restrict__ rowW,
    int* __restrict__ rowK, int* __restrict__ top2e, float* __restrict__ top2w)
{
    int b = blockIdx.x;
    int tid = threadIdx.x;
    float acc[8];
#pragma unroll
    for (int e = 0; e < 8; ++e) acc[e] = 0.f;

    const float* hb = h + (size_t)b * D_FEAT;
    for (int d = tid; d < D_FEAT; d += 256) {
        float hv = hb[d];
        float4 g0 = *(const float4*)(gw + (size_t)d * 8);
        float4 g1 = *(const float4*)(gw + (size_t)d * 8 + 4);
        acc[0] = fmaf(hv, g0.x, acc[0]);
        acc[1] = fmaf(hv, g0.y, acc[1]);
        acc[2] = fmaf(hv, g0.z, acc[2]);
        acc[3] = fmaf(hv, g0.w, acc[3]);
        acc[4] = fmaf(hv, g1.x, acc[4]);
        acc[5] = fmaf(hv, g1.y, acc[5]);
        acc[6] = fmaf(hv, g1.z, acc[6]);
        acc[7] = fmaf(hv, g1.w, acc[7]);
    }

#pragma unroll
    for (int e = 0; e < 8; ++e) {
        float v = acc[e];
        v += __shfl_down(v, 32, 64);
        v += __shfl_down(v, 16, 64);
        v += __shfl_down(v, 8, 64);
        v += __shfl_down(v, 4, 64);
        v += __shfl_down(v, 2, 64);
        v += __shfl_down(v, 1, 64);
        acc[e] = v;
    }

    __shared__ float sm[4][8];
    int wid = tid >> 6, ln = tid & 63;
    if (ln == 0) {
#pragma unroll
        for (int e = 0; e < 8; ++e) sm[wid][e] = acc[e];
    }
    __syncthreads();

    if (tid == 0) {
        float lg[8], p[8];
        float m = -1e30f;
#pragma unroll
        for (int e = 0; e < 8; ++e) {
            lg[e] = sm[0][e] + sm[1][e] + sm[2][e] + sm[3][e] + gb[e];
            m = fmaxf(m, lg[e]);
        }
        float s = 0.f;
#pragma unroll
        for (int e = 0; e < 8; ++e) { p[e] = expf(lg[e] - m); s += p[e]; }
        float inv = 1.f / s;
#pragma unroll
        for (int e = 0; e < 8; ++e) p[e] *= inv;

        int i0 = 0;
#pragma unroll
        for (int e = 1; e < 8; ++e) if (p[e] > p[i0]) i0 = e;
        int i1 = (i0 == 0) ? 1 : 0;
#pragma unroll
        for (int e = 0; e < 8; ++e) if (e != i0 && p[e] > p[i1]) i1 = e;

        int pos0 = atomicAdd(&cnt[i0], 1);
        rowIdx[i0 * 128 + pos0] = b;
        rowW[i0 * 128 + pos0] = p[i0];
        rowK[i0 * 128 + pos0] = 0;
        int pos1 = atomicAdd(&cnt[i1], 1);
        rowIdx[i1 * 128 + pos1] = b;
        rowW[i1 * 128 + pos1] = p[i1];
        rowK[i1 * 128 + pos1] = 1;

        top2e[b * 2]     = i0;
        top2e[b * 2 + 1] = i1;
        top2w[b * 2]     = p[i0];
        top2w[b * 2 + 1] = p[i1];
    }
}

// float2-column FMA: acc(2 cols) += hv(4 dims) dot W rows
#define FMA_ROW2(A, HV, W0, W1, W2, W3)                         \
    do {                                                        \
        (A).x = fmaf((HV).x, (W0).x, (A).x);                    \
        (A).x = fmaf((HV).y, (W1).x, (A).x);                    \
        (A).x = fmaf((HV).z, (W2).x, (A).x);                    \
        (A).x = fmaf((HV).w, (W3).x, (A).x);                    \
        (A).y = fmaf((HV).x, (W0).y, (A).y);                    \
        (A).y = fmaf((HV).y, (W1).y, (A).y);                    \
        (A).y = fmaf((HV).z, (W2).y, (A).y);                    \
        (A).y = fmaf((HV).w, (W3).y, (A).y);                    \
    } while (0)

// ---------------- K4: grouped expert GEMM, W read ~once per (s,e) tier
// grid = rc(4, HIGH bits, sparse) x e(8) x s(64, LOW bits -> XCDs).
// block 512 thr: 500 active x 2 cols (float2), RMAX=32 rows in registers.
// NO min-waves clause (R6/R13 lesson): acc 64 + buf 16 + misc ~ 100 VGPR.
__global__ __launch_bounds__(512) void k4_expert(
    const float* __restrict__ h, const float* __restrict__ ew,
    const int* __restrict__ cnt, const int* __restrict__ rowIdx,
    const float* __restrict__ rowW, const int* __restrict__ rowK,
    float* __restrict__ part)
{
    __shared__ float h_lds[RMAX * DSL];         // 25088 B
    __shared__ int   roff_s[RMAX];

    int tid  = threadIdx.x;
    int bid  = blockIdx.x;
    int rc   = bid >> 9;                 // 0..3 (tiers of 32 rows)
    int base = bid & 511;
    int s    = base & 63;                // LOW bits: uniform across XCDs
    int e    = base >> 6;

    int n = cnt[e];
    int rbase = rc * RMAX;
    if (rbase >= n) return;
    int nrows = n - rbase; if (nrows > RMAX) nrows = RMAX;

    if (tid < RMAX) {
        roff_s[tid] = (tid < nrows) ? rowIdx[e * 128 + rbase + tid] * D_FEAT : -1;
    }
    __syncthreads();

    int dbase = s * DSL;
    // stage h rows [RMAX x DSL] into LDS (zeros for invalid rows)
    for (int i = tid; i < RMAX * NIT4; i += 512) {
        int r = i / NIT4;
        int q = i - r * NIT4;
        int ro = roff_s[r];
        float4 v = make_float4(0.f, 0.f, 0.f, 0.f);
        if (ro >= 0) v = *(const float4*)(h + ro + dbase + q * 4);
        *(float4*)&h_lds[r * DSL + q * 4] = v;
    }
    __syncthreads();

    if (tid < 500) {                      // 500 active threads, 2 cols each
        const float* wp = ew + ((size_t)e * D_FEAT + dbase) * NC + tid * 2;

        float2 acc[RMAX];
#pragma unroll
        for (int r = 0; r < RMAX; ++r) acc[r] = make_float2(0.f, 0.f);

        float2 wA0 = *(const float2*)(wp);
        float2 wA1 = *(const float2*)(wp + (size_t)NC);
        float2 wA2 = *(const float2*)(wp + (size_t)2 * NC);
        float2 wA3 = *(const float2*)(wp + (size_t)3 * NC);

        for (int it = 0; it < NIT4; ++it) {
            const float* np = wp + (size_t)4 * NC;
            float2 wB0, wB1, wB2, wB3;
            if (it < NIT4 - 1) {
                wB0 = *(const float2*)(np);
                wB1 = *(const float2*)(np + (size_t)NC);
                wB2 = *(const float2*)(np + (size_t)2 * NC);
                wB3 = *(const float2*)(np + (size_t)3 * NC);
            }
            const float* hp = &h_lds[it * 4];
#pragma unroll
            for (int r = 0; r < RMAX; ++r) {     // unconditional: pad rows zero
                float4 hv = *(const float4*)(hp + r * DSL);
                FMA_ROW2(acc[r], hv, wA0, wA1, wA2, wA3);
            }
            wp = np;
            wA0 = wB0; wA1 = wB1; wA2 = wB2; wA3 = wB3;
        }

#pragma unroll
        for (int r = 0; r < RMAX; ++r) {
            if (r < nrows) {
                int pos = e * 128 + rbase + r;
                float wgt = rowW[pos];
                int ri = rowIdx[pos];
                int kk = rowK[pos];
                float2 o = make_float2(wgt * acc[r].x, wgt * acc[r].y);
                *(float2*)&part[(((size_t)s * 128 + ri) * 2 + kk) * NC + tid * 2] = o;
            }
        }
    }
}

// ---------------- K5: sum partials + weighted expert bias, row softmax
__global__ __launch_bounds__(256) void k5_softmax(
    const float* __restrict__ part, const float* __restrict__ eb,
    const int* __restrict__ top2e, const float* __restrict__ top2w,
    float* __restrict__ out)
{
    int b = blockIdx.x;
    int tid = threadIdx.x;
    __shared__ float red[4];

    int e0 = top2e[b * 2], e1 = top2e[b * 2 + 1];
    float tw0 = top2w[b * 2], tw1 = top2w[b * 2 + 1];

    bool act = (tid < 250);
    int c0 = tid * 4;
    float4 v = make_float4(-1e30f, -1e30f, -1e30f, -1e30f);
    if (act) {
        float4 a = make_float4(0.f, 0.f, 0.f, 0.f);
        for (int s = 0; s < S64; ++s) {
            const float* p0 = part + (((size_t)s * 128 + b) * 2) * NC + c0;
            float4 q0 = *(const float4*)p0;
            float4 q1 = *(const float4*)(p0 + NC);
            a.x += q0.x + q1.x;
            a.y += q0.y + q1.y;
            a.z += q0.z + q1.z;
            a.w += q0.w + q1.w;
        }
        float4 b0 = *(const float4*)(eb + e0 * NC + c0);
        float4 b1 = *(const float4*)(eb + e1 * NC + c0);
        v.x = a.x + tw0 * b0.x + tw1 * b1.x;
        v.y = a.y + tw0 * b0.y + tw1 * b1.y;
        v.z = a.z + tw0 * b0.z + tw1 * b1.z;
        v.w = a.w + tw0 * b0.w + tw1 * b1.w;
    }

    float m = fmaxf(fmaxf(v.x, v.y), fmaxf(v.z, v.w));
#pragma unroll
    for (int off = 32; off >= 1; off >>= 1)
        m = fmaxf(m, __shfl_xor(m, off, 64));
    int wid = tid >> 6, ln = tid & 63;
    if (ln == 0) red[wid] = m;
    __syncthreads();
    m = fmaxf(fmaxf(red[0], red[1]), fmaxf(red[2], red[3]));
    __syncthreads();

    float ex, ey, ez, ew2;
    ex = act ? expf(v.x - m) : 0.f;
    ey = act ? expf(v.y - m) : 0.f;
    ez = act ? expf(v.z - m) : 0.f;
    ew2 = act ? expf(v.w - m) : 0.f;
    float ssum = ex + ey + ez + ew2;
#pragma unroll
    for (int off = 32; off >= 1; off >>= 1)
        ssum += __shfl_xor(ssum, off, 64);
    if (ln == 0) red[wid] = ssum;
    __syncthreads();
    ssum = red[0] + red[1] + red[2] + red[3];
    float inv = 1.f / ssum;

    if (act) {
        float4 o = make_float4(ex * inv, ey * inv, ez * inv, ew2 * inv);
        *(float4*)&out[(size_t)b * NC + c0] = o;
    }
}

extern "C" void kernel_launch(void* const* d_in, const int* in_sizes, int n_in,
                              void* d_out, int out_size, void* d_ws, size_t ws_size,
                              hipStream_t stream) {
    const float* x   = (const float*)d_in[0];
    const float* c1w = (const float*)d_in[1];
    const float* c1b = (const float*)d_in[2];
    const float* c2w = (const float*)d_in[3];
    const float* c2b = (const float*)d_in[4];
    const float* gw  = (const float*)d_in[5];
    const float* gb  = (const float*)d_in[6];
    const float* ew  = (const float*)d_in[7];
    const float* eb  = (const float*)d_in[8];
    float* out = (float*)d_out;

    char* ws = (char*)d_ws;
    // layout (part overlays dead h1 region):
    //   smalls:  0 .. 16384
    //   h:       16384 .. 6438912                  (6,422,528 B)
    //   h1:      6438912 .. 22183936               (15,745,024 B, dead after k2)
    //   part:    6438912 .. 71974912               (65,536,000 B, alive k4..k5)
    int*   cnt    = (int*)  (ws + 0);        //    32 B
    int*   rowIdx = (int*)  (ws + 64);       //  4096 B
    float* rowW   = (float*)(ws + 4160);     //  4096 B
    int*   rowK   = (int*)  (ws + 8256);     //  4096 B
    int*   top2e  = (int*)  (ws + 12352);    //  1024 B
    float* top2w  = (float*)(ws + 13376);    //  1024 B
    float* h      = (float*)(ws + 16384);
    float* h1     = (float*)(ws + 6438912);
    float* part   = (float*)(ws + 6438912);

    k1_conv1<<<128 * 31 * 4, 256, 0, stream>>>(x, c1w, c1b, h1, cnt);
    k2_conv2<<<128 * 14 * 2, 448, 0, stream>>>(h1, c2w, c2b, h);
    k3_gate<<<128, 256, 0, stream>>>(h, gw, gb, cnt, rowIdx, rowW, rowK, top2e, top2w);
    k4_expert<<<4 * 8 * 64, 512, 0, stream>>>(h, ew, cnt, rowIdx, rowW, rowK, part);
    k5_softmax<<<128, 256, 0, stream>>>(part, eb, top2e, top2w, out);
}

// Round 15
// 319.821 us; speedup vs baseline: 1.2680x; 1.2310x over previous
//
#include <hip/hip_runtime.h>
#include <math.h>

#define D_FEAT 12544
#define NC 1000
#define RMAX 32        // rows per k4 tier (2 groups x 16)
#define S64 64         // global D slices
#define DSL 196        // D_FEAT / S64
#define NIT4 (DSL/4)   // 49 d4 iterations

// ---------------- K1: conv1(1->32,3x3,VALID)+ReLU+maxpool2 -> h1[128,31,31,32]
__global__ __launch_bounds__(256) void k1_conv1(
    const float* __restrict__ x, const float* __restrict__ w,
    const float* __restrict__ bias, float* __restrict__ h1,
    int* __restrict__ cnt)
{
    // zero routing counters (stream-ordered before k3)
    if (blockIdx.x == 0 && threadIdx.x < 8) cnt[threadIdx.x] = 0;

    int co  = threadIdx.x & 31;
    int pxi = threadIdx.x >> 5;          // 0..7
    int blk = blockIdx.x;
    int pxg = blk & 3;
    int py  = (blk >> 2) % 31;
    int b   = blk / (31 * 4);
    int px  = pxg * 8 + pxi;
    if (px >= 31) return;

    float wr[9];
#pragma unroll
    for (int t = 0; t < 9; ++t) wr[t] = w[t * 32 + co];
    float bb = bias[co];

    float in[4][4];
    const float* xb = x + ((size_t)(b * 64 + 2 * py) * 64 + 2 * px);
#pragma unroll
    for (int r = 0; r < 4; ++r)
#pragma unroll
        for (int c = 0; c < 4; ++c)
            in[r][c] = xb[r * 64 + c];

    float a00 = 0.f, a01 = 0.f, a10 = 0.f, a11 = 0.f;
#pragma unroll
    for (int ky = 0; ky < 3; ++ky)
#pragma unroll
        for (int kx = 0; kx < 3; ++kx) {
            float wv = wr[ky * 3 + kx];
            a00 = fmaf(in[ky][kx],     wv, a00);
            a01 = fmaf(in[ky][kx + 1], wv, a01);
            a10 = fmaf(in[ky + 1][kx], wv, a10);
            a11 = fmaf(in[ky + 1][kx + 1], wv, a11);
        }
    a00 = fmaxf(a00 + bb, 0.f);
    a01 = fmaxf(a01 + bb, 0.f);
    a10 = fmaxf(a10 + bb, 0.f);
    a11 = fmaxf(a11 + bb, 0.f);
    float v = fmaxf(fmaxf(a00, a01), fmaxf(a10, a11));
    h1[((size_t)(b * 31 + py) * 31 + px) * 32 + co] = v;
}

// ---------------- K2: conv2(32->64,3x3,VALID)+ReLU+maxpool2 -> h[128,14,14,64]
__global__ __launch_bounds__(448) void k2_conv2(
    const float* __restrict__ h1, const float* __restrict__ w2,
    const float* __restrict__ b2, float* __restrict__ h)
{
    __shared__ float wl[9 * 32 * 32];    // [tap][ci][co_local] 36864 B

    int co  = threadIdx.x & 31;
    int px  = threadIdx.x >> 5;          // 0..13
    int blk = blockIdx.x;
    int cob = blk & 1;
    int py  = (blk >> 1) % 14;
    int b   = blk / 28;

    for (int i = threadIdx.x; i < 9 * 32 * 32; i += 448) {
        int tapci = i >> 5;
        int col   = i & 31;
        wl[i] = w2[tapci * 64 + cob * 32 + col];
    }
    __syncthreads();

    float acc00 = 0.f, acc01 = 0.f, acc10 = 0.f, acc11 = 0.f;
    const float* base = h1 + ((size_t)(b * 31 + 2 * py) * 31 + 2 * px) * 32;

    for (int q = 0; q < 8; ++q) {
        float4 in4[4][4];
#pragma unroll
        for (int r = 0; r < 4; ++r)
#pragma unroll
            for (int c = 0; c < 4; ++c)
                in4[r][c] = *(const float4*)(base + (r * 31 + c) * 32 + q * 4);

#pragma unroll
        for (int ky = 0; ky < 3; ++ky)
#pragma unroll
            for (int kx = 0; kx < 3; ++kx) {
                int tap = ky * 3 + kx;
                const float* wp = &wl[(tap * 32 + q * 4) * 32 + co];
                float w0 = wp[0];
                float w1 = wp[32];
                float w2v = wp[64];
                float w3 = wp[96];
                acc00 = fmaf(in4[ky][kx].x, w0, acc00);
                acc00 = fmaf(in4[ky][kx].y, w1, acc00);
                acc00 = fmaf(in4[ky][kx].z, w2v, acc00);
                acc00 = fmaf(in4[ky][kx].w, w3, acc00);
                acc01 = fmaf(in4[ky][kx + 1].x, w0, acc01);
                acc01 = fmaf(in4[ky][kx + 1].y, w1, acc01);
                acc01 = fmaf(in4[ky][kx + 1].z, w2v, acc01);
                acc01 = fmaf(in4[ky][kx + 1].w, w3, acc01);
                acc10 = fmaf(in4[ky + 1][kx].x, w0, acc10);
                acc10 = fmaf(in4[ky + 1][kx].y, w1, acc10);
                acc10 = fmaf(in4[ky + 1][kx].z, w2v, acc10);
                acc10 = fmaf(in4[ky + 1][kx].w, w3, acc10);
                acc11 = fmaf(in4[ky + 1][kx + 1].x, w0, acc11);
                acc11 = fmaf(in4[ky + 1][kx + 1].y, w1, acc11);
                acc11 = fmaf(in4[ky + 1][kx + 1].z, w2v, acc11);
                acc11 = fmaf(in4[ky + 1][kx + 1].w, w3, acc11);
            }
    }

    float bb = b2[cob * 32 + co];
    acc00 = fmaxf(acc00 + bb, 0.f);
    acc01 = fmaxf(acc01 + bb, 0.f);
    acc10 = fmaxf(acc10 + bb, 0.f);
    acc11 = fmaxf(acc11 + bb, 0.f);
    float v = fmaxf(fmaxf(acc00, acc01), fmaxf(acc10, acc11));
    h[(size_t)b * D_FEAT + (py * 14 + px) * 64 + cob * 32 + co] = v;
}

// ---------------- K3: gate logits + softmax + top2 + routing lists (with k index)
__global__ __launch_bounds__(256) void k3_gate(
    const float* __restrict__ h, const float* __restrict__ gw,
    const float* __restrict__ gb, int* __restrict__ cnt,
    int* __restrict__ rowIdx, float* __restrict__ rowW,
    int* __restrict__ rowK, int* __restrict__ top2e, float* __restrict__ top2w)
{
    int b = blockIdx.x;
    int tid = threadIdx.x;
    float acc[8];
#pragma unroll
    for (int e = 0; e < 8; ++e) acc[e] = 0.f;

    const float* hb = h + (size_t)b * D_FEAT;
    for (int d = tid; d < D_FEAT; d += 256) {
        float hv = hb[d];
        float4 g0 = *(const float4*)(gw + (size_t)d * 8);
        float4 g1 = *(const float4*)(gw + (size_t)d * 8 + 4);
        acc[0] = fmaf(hv, g0.x, acc[0]);
        acc[1] = fmaf(hv, g0.y, acc[1]);
        acc[2] = fmaf(hv, g0.z, acc[2]);
        acc[3] = fmaf(hv, g0.w, acc[3]);
        acc[4] = fmaf(hv, g1.x, acc[4]);
        acc[5] = fmaf(hv, g1.y, acc[5]);
        acc[6] = fmaf(hv, g1.z, acc[6]);
        acc[7] = fmaf(hv, g1.w, acc[7]);
    }

#pragma unroll
    for (int e = 0; e < 8; ++e) {
        float v = acc[e];
        v += __shfl_down(v, 32, 64);
        v += __shfl_down(v, 16, 64);
        v += __shfl_down(v, 8, 64);
        v += __shfl_down(v, 4, 64);
        v += __shfl_down(v, 2, 64);
        v += __shfl_down(v, 1, 64);
        acc[e] = v;
    }

    __shared__ float sm[4][8];
    int wid = tid >> 6, ln = tid & 63;
    if (ln == 0) {
#pragma unroll
        for (int e = 0; e < 8; ++e) sm[wid][e] = acc[e];
    }
    __syncthreads();

    if (tid == 0) {
        float lg[8], p[8];
        float m = -1e30f;
#pragma unroll
        for (int e = 0; e < 8; ++e) {
            lg[e] = sm[0][e] + sm[1][e] + sm[2][e] + sm[3][e] + gb[e];
            m = fmaxf(m, lg[e]);
        }
        float s = 0.f;
#pragma unroll
        for (int e = 0; e < 8; ++e) { p[e] = expf(lg[e] - m); s += p[e]; }
        float inv = 1.f / s;
#pragma unroll
        for (int e = 0; e < 8; ++e) p[e] *= inv;

        int i0 = 0;
#pragma unroll
        for (int e = 1; e < 8; ++e) if (p[e] > p[i0]) i0 = e;
        int i1 = (i0 == 0) ? 1 : 0;
#pragma unroll
        for (int e = 0; e < 8; ++e) if (e != i0 && p[e] > p[i1]) i1 = e;

        int pos0 = atomicAdd(&cnt[i0], 1);
        rowIdx[i0 * 128 + pos0] = b;
        rowW[i0 * 128 + pos0] = p[i0];
        rowK[i0 * 128 + pos0] = 0;
        int pos1 = atomicAdd(&cnt[i1], 1);
        rowIdx[i1 * 128 + pos1] = b;
        rowW[i1 * 128 + pos1] = p[i1];
        rowK[i1 * 128 + pos1] = 1;

        top2e[b * 2]     = i0;
        top2e[b * 2 + 1] = i1;
        top2w[b * 2]     = p[i0];
        top2w[b * 2 + 1] = p[i1];
    }
}

#define FMA_ROW(A, HV, W0, W1, W2, W3)                          \
    do {                                                        \
        (A).x = fmaf((HV).x, (W0).x, (A).x);                    \
        (A).x = fmaf((HV).y, (W1).x, (A).x);                    \
        (A).x = fmaf((HV).z, (W2).x, (A).x);                    \
        (A).x = fmaf((HV).w, (W3).x, (A).x);                    \
        (A).y = fmaf((HV).x, (W0).y, (A).y);                    \
        (A).y = fmaf((HV).y, (W1).y, (A).y);                    \
        (A).y = fmaf((HV).z, (W2).y, (A).y);                    \
        (A).y = fmaf((HV).w, (W3).y, (A).y);                    \
        (A).z = fmaf((HV).x, (W0).z, (A).z);                    \
        (A).z = fmaf((HV).y, (W1).z, (A).z);                    \
        (A).z = fmaf((HV).z, (W2).z, (A).z);                    \
        (A).z = fmaf((HV).w, (W3).z, (A).z);                    \
        (A).w = fmaf((HV).x, (W0).w, (A).w);                    \
        (A).w = fmaf((HV).y, (W1).w, (A).w);                    \
        (A).w = fmaf((HV).z, (W2).w, (A).w);                    \
        (A).w = fmaf((HV).w, (W3).w, (A).w);                    \
    } while (0)

// ---------------- K4: grouped expert GEMM — dedupe tiers + full-row float4 coalescing
// grid = rc(4, HIGH bits, sparse) x e(8) x s(64, LOW bits -> XCDs).
// block 512 = 2 row-groups x 256 thr; each group: 16 rows x 1000 cols, float4 W
// loads (1 KB/wave-instr, 16 KB contiguous/iter). Group B re-reads group A's W
// addresses -> L1/L2-same-XCD hits. Logical W traffic 1.25x -> L3 retention.
__global__ __launch_bounds__(512) void k4_expert(
    const float* __restrict__ h, const float* __restrict__ ew,
    const int* __restrict__ cnt, const int* __restrict__ rowIdx,
    const float* __restrict__ rowW, const int* __restrict__ rowK,
    float* __restrict__ part)
{
    __shared__ float h_lds[RMAX * DSL];         // 25088 B
    __shared__ int   roff_s[RMAX];

    int tid  = threadIdx.x;
    int bid  = blockIdx.x;
    int rc   = bid >> 9;                 // 0..3 (tiers of 32 rows)
    int base = bid & 511;
    int s    = base & 63;                // LOW bits: uniform across XCDs
    int e    = base >> 6;

    int n = cnt[e];
    int rbase = rc * RMAX;
    if (rbase >= n) return;
    int nrows = n - rbase; if (nrows > RMAX) nrows = RMAX;

    if (tid < RMAX) {
        roff_s[tid] = (tid < nrows) ? rowIdx[e * 128 + rbase + tid] * D_FEAT : -1;
    }
    __syncthreads();

    int dbase = s * DSL;
    // stage h rows [RMAX x DSL] into LDS (zeros for invalid rows)
    for (int i = tid; i < RMAX * NIT4; i += 512) {
        int r = i / NIT4;
        int q = i - r * NIT4;
        int ro = roff_s[r];
        float4 v = make_float4(0.f, 0.f, 0.f, 0.f);
        if (ro >= 0) v = *(const float4*)(h + ro + dbase + q * 4);
        *(float4*)&h_lds[r * DSL + q * 4] = v;
    }
    __syncthreads();

    int grp  = tid >> 8;                 // 0: rows 0-15, 1: rows 16-31
    int ct   = tid & 255;                // col-thread within group
    int rofs = grp * 16;
    int c0   = ct * 4;
    if (c0 < NC) {                        // 250 active col-threads per group
        const float* wp = ew + ((size_t)e * D_FEAT + dbase) * NC + c0;

        float4 acc[16];
#pragma unroll
        for (int r = 0; r < 16; ++r) acc[r] = make_float4(0.f, 0.f, 0.f, 0.f);

        float4 wA0 = *(const float4*)(wp);
        float4 wA1 = *(const float4*)(wp + (size_t)NC);
        float4 wA2 = *(const float4*)(wp + (size_t)2 * NC);
        float4 wA3 = *(const float4*)(wp + (size_t)3 * NC);

        const float* hbase = &h_lds[rofs * DSL];
        for (int it = 0; it < NIT4; ++it) {
            const float* np = wp + (size_t)4 * NC;
            float4 wB0, wB1, wB2, wB3;
            if (it < NIT4 - 1) {
                wB0 = *(const float4*)(np);
                wB1 = *(const float4*)(np + (size_t)NC);
                wB2 = *(const float4*)(np + (size_t)2 * NC);
                wB3 = *(const float4*)(np + (size_t)3 * NC);
            }
            const float* hp = hbase + it * 4;
#pragma unroll
            for (int r = 0; r < 16; ++r) {       // unconditional: pad rows zero
                float4 hv = *(const float4*)(hp + r * DSL);
                FMA_ROW(acc[r], hv, wA0, wA1, wA2, wA3);
            }
            wp = np;
            wA0 = wB0; wA1 = wB1; wA2 = wB2; wA3 = wB3;
        }

#pragma unroll
        for (int r = 0; r < 16; ++r) {
            int gr = rofs + r;
            if (gr < nrows) {
                int pos = e * 128 + rbase + gr;
                float wgt = rowW[pos];
                int ri = rowIdx[pos];
                int kk = rowK[pos];
                float4 o = make_float4(wgt * acc[r].x, wgt * acc[r].y,
                                       wgt * acc[r].z, wgt * acc[r].w);
                *(float4*)&part[(((size_t)s * 128 + ri) * 2 + kk) * NC + c0] = o;
            }
        }
    }
}

// ---------------- K5: sum partials + weighted expert bias, row softmax
__global__ __launch_bounds__(256) void k5_softmax(
    const float* __restrict__ part, const float* __restrict__ eb,
    const int* __restrict__ top2e, const float* __restrict__ top2w,
    float* __restrict__ out)
{
    int b = blockIdx.x;
    int tid = threadIdx.x;
    __shared__ float red[4];

    int e0 = top2e[b * 2], e1 = top2e[b * 2 + 1];
    float tw0 = top2w[b * 2], tw1 = top2w[b * 2 + 1];

    bool act = (tid < 250);
    int c0 = tid * 4;
    float4 v = make_float4(-1e30f, -1e30f, -1e30f, -1e30f);
    if (act) {
        float4 a = make_float4(0.f, 0.f, 0.f, 0.f);
        for (int s = 0; s < S64; ++s) {
            const float* p0 = part + (((size_t)s * 128 + b) * 2) * NC + c0;
            float4 q0 = *(const float4*)p0;
            float4 q1 = *(const float4*)(p0 + NC);
            a.x += q0.x + q1.x;
            a.y += q0.y + q1.y;
            a.z += q0.z + q1.z;
            a.w += q0.w + q1.w;
        }
        float4 b0 = *(const float4*)(eb + e0 * NC + c0);
        float4 b1 = *(const float4*)(eb + e1 * NC + c0);
        v.x = a.x + tw0 * b0.x + tw1 * b1.x;
        v.y = a.y + tw0 * b0.y + tw1 * b1.y;
        v.z = a.z + tw0 * b0.z + tw1 * b1.z;
        v.w = a.w + tw0 * b0.w + tw1 * b1.w;
    }

    float m = fmaxf(fmaxf(v.x, v.y), fmaxf(v.z, v.w));
#pragma unroll
    for (int off = 32; off >= 1; off >>= 1)
        m = fmaxf(m, __shfl_xor(m, off, 64));
    int wid = tid >> 6, ln = tid & 63;
    if (ln == 0) red[wid] = m;
    __syncthreads();
    m = fmaxf(fmaxf(red[0], red[1]), fmaxf(red[2], red[3]));
    __syncthreads();

    float ex, ey, ez, ew2;
    ex = act ? expf(v.x - m) : 0.f;
    ey = act ? expf(v.y - m) : 0.f;
    ez = act ? expf(v.z - m) : 0.f;
    ew2 = act ? expf(v.w - m) : 0.f;
    float ssum = ex + ey + ez + ew2;
#pragma unroll
    for (int off = 32; off >= 1; off >>= 1)
        ssum += __shfl_xor(ssum, off, 64);
    if (ln == 0) red[wid] = ssum;
    __syncthreads();
    ssum = red[0] + red[1] + red[2] + red[3];
    float inv = 1.f / ssum;

    if (act) {
        float4 o = make_float4(ex * inv, ey * inv, ez * inv, ew2 * inv);
        *(float4*)&out[(size_t)b * NC + c0] = o;
    }
}

extern "C" void kernel_launch(void* const* d_in, const int* in_sizes, int n_in,
                              void* d_out, int out_size, void* d_ws, size_t ws_size,
                              hipStream_t stream) {
    const float* x   = (const float*)d_in[0];
    const float* c1w = (const float*)d_in[1];
    const float* c1b = (const float*)d_in[2];
    const float* c2w = (const float*)d_in[3];
    const float* c2b = (const float*)d_in[4];
    const float* gw  = (const float*)d_in[5];
    const float* gb  = (const float*)d_in[6];
    const float* ew  = (const float*)d_in[7];
    const float* eb  = (const float*)d_in[8];
    float* out = (float*)d_out;

    char* ws = (char*)d_ws;
    // layout (part overlays dead h1 region):
    //   smalls:  0 .. 16384
    //   h:       16384 .. 6438912                  (6,422,528 B)
    //   h1:      6438912 .. 22183936               (15,745,024 B, dead after k2)
    //   part:    6438912 .. 71974912               (65,536,000 B, alive k4..k5)
    int*   cnt    = (int*)  (ws + 0);        //    32 B
    int*   rowIdx = (int*)  (ws + 64);       //  4096 B
    float* rowW   = (float*)(ws + 4160);     //  4096 B
    int*   rowK   = (int*)  (ws + 8256);     //  4096 B
    int*   top2e  = (int*)  (ws + 12352);    //  1024 B
    float* top2w  = (float*)(ws + 13376);    //  1024 B
    float* h      = (float*)(ws + 16384);
    float* h1     = (float*)(ws + 6438912);
    float* part   = (float*)(ws + 6438912);

    k1_conv1<<<128 * 31 * 4, 256, 0, stream>>>(x, c1w, c1b, h1, cnt);
    k2_conv2<<<128 * 14 * 2, 448, 0, stream>>>(h1, c2w, c2b, h);
    k3_gate<<<128, 256, 0, stream>>>(h, gw, gb, cnt, rowIdx, rowW, rowK, top2e, top2w);
    k4_expert<<<4 * 8 * 64, 512, 0, stream>>>(h, ew, cnt, rowIdx, rowW, rowK, part);
    k5_softmax<<<128, 256, 0, stream>>>(part, eb, top2e, top2w, out);
}

// Round 16
// 291.097 us; speedup vs baseline: 1.3932x; 1.0987x over previous
//
#include <hip/hip_runtime.h>
#include <math.h>

#define D_FEAT 12544
#define NC 1000
#define RB 16          // rows per k4 block
#define S4 32          // global D slices
#define DSLICE 392     // D_FEAT / S4
#define NIT (DSLICE/4) // 98 d4 iterations
#define CT2 500        // cols per ct-half

// ---------------- K1: conv1(1->32,3x3,VALID)+ReLU+maxpool2 -> h1[128,31,31,32]
__global__ __launch_bounds__(256) void k1_conv1(
    const float* __restrict__ x, const float* __restrict__ w,
    const float* __restrict__ bias, float* __restrict__ h1,
    int* __restrict__ cnt)
{
    // zero routing counters (stream-ordered before k3)
    if (blockIdx.x == 0 && threadIdx.x < 8) cnt[threadIdx.x] = 0;

    int co  = threadIdx.x & 31;
    int pxi = threadIdx.x >> 5;          // 0..7
    int blk = blockIdx.x;
    int pxg = blk & 3;
    int py  = (blk >> 2) % 31;
    int b   = blk / (31 * 4);
    int px  = pxg * 8 + pxi;
    if (px >= 31) return;

    float wr[9];
#pragma unroll
    for (int t = 0; t < 9; ++t) wr[t] = w[t * 32 + co];
    float bb = bias[co];

    float in[4][4];
    const float* xb = x + ((size_t)(b * 64 + 2 * py) * 64 + 2 * px);
#pragma unroll
    for (int r = 0; r < 4; ++r)
#pragma unroll
        for (int c = 0; c < 4; ++c)
            in[r][c] = xb[r * 64 + c];

    float a00 = 0.f, a01 = 0.f, a10 = 0.f, a11 = 0.f;
#pragma unroll
    for (int ky = 0; ky < 3; ++ky)
#pragma unroll
        for (int kx = 0; kx < 3; ++kx) {
            float wv = wr[ky * 3 + kx];
            a00 = fmaf(in[ky][kx],     wv, a00);
            a01 = fmaf(in[ky][kx + 1], wv, a01);
            a10 = fmaf(in[ky + 1][kx], wv, a10);
            a11 = fmaf(in[ky + 1][kx + 1], wv, a11);
        }
    a00 = fmaxf(a00 + bb, 0.f);
    a01 = fmaxf(a01 + bb, 0.f);
    a10 = fmaxf(a10 + bb, 0.f);
    a11 = fmaxf(a11 + bb, 0.f);
    float v = fmaxf(fmaxf(a00, a01), fmaxf(a10, a11));
    h1[((size_t)(b * 31 + py) * 31 + px) * 32 + co] = v;
}

// ---------------- K2: conv2(32->64,3x3,VALID)+ReLU+maxpool2 -> h[128,14,14,64]
__global__ __launch_bounds__(448) void k2_conv2(
    const float* __restrict__ h1, const float* __restrict__ w2,
    const float* __restrict__ b2, float* __restrict__ h)
{
    __shared__ float wl[9 * 32 * 32];    // [tap][ci][co_local] 36864 B

    int co  = threadIdx.x & 31;
    int px  = threadIdx.x >> 5;          // 0..13
    int blk = blockIdx.x;
    int cob = blk & 1;
    int py  = (blk >> 1) % 14;
    int b   = blk / 28;

    for (int i = threadIdx.x; i < 9 * 32 * 32; i += 448) {
        int tapci = i >> 5;
        int col   = i & 31;
        wl[i] = w2[tapci * 64 + cob * 32 + col];
    }
    __syncthreads();

    float acc00 = 0.f, acc01 = 0.f, acc10 = 0.f, acc11 = 0.f;
    const float* base = h1 + ((size_t)(b * 31 + 2 * py) * 31 + 2 * px) * 32;

    for (int q = 0; q < 8; ++q) {
        float4 in4[4][4];
#pragma unroll
        for (int r = 0; r < 4; ++r)
#pragma unroll
            for (int c = 0; c < 4; ++c)
                in4[r][c] = *(const float4*)(base + (r * 31 + c) * 32 + q * 4);

#pragma unroll
        for (int ky = 0; ky < 3; ++ky)
#pragma unroll
            for (int kx = 0; kx < 3; ++kx) {
                int tap = ky * 3 + kx;
                const float* wp = &wl[(tap * 32 + q * 4) * 32 + co];
                float w0 = wp[0];
                float w1 = wp[32];
                float w2v = wp[64];
                float w3 = wp[96];
                acc00 = fmaf(in4[ky][kx].x, w0, acc00);
                acc00 = fmaf(in4[ky][kx].y, w1, acc00);
                acc00 = fmaf(in4[ky][kx].z, w2v, acc00);
                acc00 = fmaf(in4[ky][kx].w, w3, acc00);
                acc01 = fmaf(in4[ky][kx + 1].x, w0, acc01);
                acc01 = fmaf(in4[ky][kx + 1].y, w1, acc01);
                acc01 = fmaf(in4[ky][kx + 1].z, w2v, acc01);
                acc01 = fmaf(in4[ky][kx + 1].w, w3, acc01);
                acc10 = fmaf(in4[ky + 1][kx].x, w0, acc10);
                acc10 = fmaf(in4[ky + 1][kx].y, w1, acc10);
                acc10 = fmaf(in4[ky + 1][kx].z, w2v, acc10);
                acc10 = fmaf(in4[ky + 1][kx].w, w3, acc10);
                acc11 = fmaf(in4[ky + 1][kx + 1].x, w0, acc11);
                acc11 = fmaf(in4[ky + 1][kx + 1].y, w1, acc11);
                acc11 = fmaf(in4[ky + 1][kx + 1].z, w2v, acc11);
                acc11 = fmaf(in4[ky + 1][kx + 1].w, w3, acc11);
            }
    }

    float bb = b2[cob * 32 + co];
    acc00 = fmaxf(acc00 + bb, 0.f);
    acc01 = fmaxf(acc01 + bb, 0.f);
    acc10 = fmaxf(acc10 + bb, 0.f);
    acc11 = fmaxf(acc11 + bb, 0.f);
    float v = fmaxf(fmaxf(acc00, acc01), fmaxf(acc10, acc11));
    h[(size_t)b * D_FEAT + (py * 14 + px) * 64 + cob * 32 + co] = v;
}

// ---------------- K3: gate logits (vectorized float4) + softmax + top2 + routing
__global__ __launch_bounds__(256) void k3_gate(
    const float* __restrict__ h, const float* __restrict__ gw,
    const float* __restrict__ gb, int* __restrict__ cnt,
    int* __restrict__ rowIdx, float* __restrict__ rowW,
    int* __restrict__ rowK, int* __restrict__ top2e, float* __restrict__ top2w)
{
    int b = blockIdx.x;
    int tid = threadIdx.x;
    float acc[8];
#pragma unroll
    for (int e = 0; e < 8; ++e) acc[e] = 0.f;

    const float* hb = h + (size_t)b * D_FEAT;
    // each iteration: 4 d's -> 1 float4 h load + 8 coalesced float4 gw loads + 32 FMA
    for (int i4 = tid; i4 < D_FEAT / 4; i4 += 256) {
        float4 hv = *(const float4*)(hb + i4 * 4);
        const float* gp = gw + (size_t)i4 * 32;
        float4 g0 = *(const float4*)(gp);       // row0 e0-3
        float4 g1 = *(const float4*)(gp + 4);   // row0 e4-7
        float4 g2 = *(const float4*)(gp + 8);   // row1 e0-3
        float4 g3 = *(const float4*)(gp + 12);  // row1 e4-7
        float4 g4 = *(const float4*)(gp + 16);  // row2 e0-3
        float4 g5 = *(const float4*)(gp + 20);  // row2 e4-7
        float4 g6 = *(const float4*)(gp + 24);  // row3 e0-3
        float4 g7 = *(const float4*)(gp + 28);  // row3 e4-7

        acc[0] = fmaf(hv.x, g0.x, acc[0]); acc[0] = fmaf(hv.y, g2.x, acc[0]);
        acc[0] = fmaf(hv.z, g4.x, acc[0]); acc[0] = fmaf(hv.w, g6.x, acc[0]);
        acc[1] = fmaf(hv.x, g0.y, acc[1]); acc[1] = fmaf(hv.y, g2.y, acc[1]);
        acc[1] = fmaf(hv.z, g4.y, acc[1]); acc[1] = fmaf(hv.w, g6.y, acc[1]);
        acc[2] = fmaf(hv.x, g0.z, acc[2]); acc[2] = fmaf(hv.y, g2.z, acc[2]);
        acc[2] = fmaf(hv.z, g4.z, acc[2]); acc[2] = fmaf(hv.w, g6.z, acc[2]);
        acc[3] = fmaf(hv.x, g0.w, acc[3]); acc[3] = fmaf(hv.y, g2.w, acc[3]);
        acc[3] = fmaf(hv.z, g4.w, acc[3]); acc[3] = fmaf(hv.w, g6.w, acc[3]);
        acc[4] = fmaf(hv.x, g1.x, acc[4]); acc[4] = fmaf(hv.y, g3.x, acc[4]);
        acc[4] = fmaf(hv.z, g5.x, acc[4]); acc[4] = fmaf(hv.w, g7.x, acc[4]);
        acc[5] = fmaf(hv.x, g1.y, acc[5]); acc[5] = fmaf(hv.y, g3.y, acc[5]);
        acc[5] = fmaf(hv.z, g5.y, acc[5]); acc[5] = fmaf(hv.w, g7.y, acc[5]);
        acc[6] = fmaf(hv.x, g1.z, acc[6]); acc[6] = fmaf(hv.y, g3.z, acc[6]);
        acc[6] = fmaf(hv.z, g5.z, acc[6]); acc[6] = fmaf(hv.w, g7.z, acc[6]);
        acc[7] = fmaf(hv.x, g1.w, acc[7]); acc[7] = fmaf(hv.y, g3.w, acc[7]);
        acc[7] = fmaf(hv.z, g5.w, acc[7]); acc[7] = fmaf(hv.w, g7.w, acc[7]);
    }

#pragma unroll
    for (int e = 0; e < 8; ++e) {
        float v = acc[e];
        v += __shfl_down(v, 32, 64);
        v += __shfl_down(v, 16, 64);
        v += __shfl_down(v, 8, 64);
        v += __shfl_down(v, 4, 64);
        v += __shfl_down(v, 2, 64);
        v += __shfl_down(v, 1, 64);
        acc[e] = v;
    }

    __shared__ float sm[4][8];
    int wid = tid >> 6, ln = tid & 63;
    if (ln == 0) {
#pragma unroll
        for (int e = 0; e < 8; ++e) sm[wid][e] = acc[e];
    }
    __syncthreads();

    if (tid == 0) {
        float lg[8], p[8];
        float m = -1e30f;
#pragma unroll
        for (int e = 0; e < 8; ++e) {
            lg[e] = sm[0][e] + sm[1][e] + sm[2][e] + sm[3][e] + gb[e];
            m = fmaxf(m, lg[e]);
        }
        float s = 0.f;
#pragma unroll
        for (int e = 0; e < 8; ++e) { p[e] = expf(lg[e] - m); s += p[e]; }
        float inv = 1.f / s;
#pragma unroll
        for (int e = 0; e < 8; ++e) p[e] *= inv;

        int i0 = 0;
#pragma unroll
        for (int e = 1; e < 8; ++e) if (p[e] > p[i0]) i0 = e;
        int i1 = (i0 == 0) ? 1 : 0;
#pragma unroll
        for (int e = 0; e < 8; ++e) if (e != i0 && p[e] > p[i1]) i1 = e;

        int pos0 = atomicAdd(&cnt[i0], 1);
        rowIdx[i0 * 128 + pos0] = b;
        rowW[i0 * 128 + pos0] = p[i0];
        rowK[i0 * 128 + pos0] = 0;
        int pos1 = atomicAdd(&cnt[i1], 1);
        rowIdx[i1 * 128 + pos1] = b;
        rowW[i1 * 128 + pos1] = p[i1];
        rowK[i1 * 128 + pos1] = 1;

        top2e[b * 2]     = i0;
        top2e[b * 2 + 1] = i1;
        top2w[b * 2]     = p[i0];
        top2w[b * 2 + 1] = p[i1];
    }
}

// float2-column FMA: acc(2 cols) += hv(4 dims) dot W rows
#define FMA_ROW2(A, HV, W0, W1, W2, W3)                         \
    do {                                                        \
        (A).x = fmaf((HV).x, (W0).x, (A).x);                    \
        (A).x = fmaf((HV).y, (W1).x, (A).x);                    \
        (A).x = fmaf((HV).z, (W2).x, (A).x);                    \
        (A).x = fmaf((HV).w, (W3).x, (A).x);                    \
        (A).y = fmaf((HV).x, (W0).y, (A).y);                    \
        (A).y = fmaf((HV).y, (W1).y, (A).y);                    \
        (A).y = fmaf((HV).z, (W2).y, (A).y);                    \
        (A).y = fmaf((HV).w, (W3).y, (A).y);                    \
    } while (0)

// ---------------- K4: grouped expert GEMM (champion R11 structure)
// grid decode: s LOW 5 bits (uniform -> all XCDs), ct, e, rc HIGH (sparse).
__global__ __launch_bounds__(256) void k4_expert(
    const float* __restrict__ h, const float* __restrict__ ew,
    const int* __restrict__ cnt, const int* __restrict__ rowIdx,
    const float* __restrict__ rowW, const int* __restrict__ rowK,
    float* __restrict__ part)
{
    __shared__ float h_lds[RB * DSLICE];        // 25088 B
    __shared__ int   roff_s[RB];

    int tid = threadIdx.x;
    int bid = blockIdx.x;
    int s  = bid & 31;                   // LOW bits: uniform across XCDs
    int ct = (bid >> 5) & 1;
    int e  = (bid >> 6) & 7;
    int rc = bid >> 9;                   // HIGH bits: sparse early-exit

    int n = cnt[e];
    int rbase = rc * RB;
    if (rbase >= n) return;
    int nrows = n - rbase; if (nrows > RB) nrows = RB;

    if (tid < RB) {
        roff_s[tid] = (tid < nrows) ? rowIdx[e * 128 + rbase + tid] * D_FEAT : -1;
    }
    __syncthreads();

    int dbase = s * DSLICE;
    // stage h rows [RB x DSLICE] into LDS (zeros for invalid rows)
    for (int i = tid; i < RB * (DSLICE / 4); i += 256) {
        int r = i / (DSLICE / 4);
        int q = i - r * (DSLICE / 4);
        int ro = roff_s[r];
        float4 v = make_float4(0.f, 0.f, 0.f, 0.f);
        if (ro >= 0) v = *(const float4*)(h + ro + dbase + q * 4);
        *(float4*)&h_lds[r * DSLICE + q * 4] = v;
    }
    __syncthreads();

    if (tid < 250) {                      // 250 active threads, 2 cols each
        const float* wp = ew + ((size_t)e * D_FEAT + dbase) * NC + ct * CT2 + tid * 2;
        bool g1 = (nrows > 8);

        float2 acc[RB];
#pragma unroll
        for (int r = 0; r < RB; ++r) acc[r] = make_float2(0.f, 0.f);

        float2 wA0 = *(const float2*)(wp);
        float2 wA1 = *(const float2*)(wp + (size_t)NC);
        float2 wA2 = *(const float2*)(wp + (size_t)2 * NC);
        float2 wA3 = *(const float2*)(wp + (size_t)3 * NC);

        for (int it = 0; it < NIT; ++it) {
            const float* np = wp + (size_t)4 * NC;
            float2 wB0, wB1, wB2, wB3;
            if (it < NIT - 1) {
                wB0 = *(const float2*)(np);
                wB1 = *(const float2*)(np + (size_t)NC);
                wB2 = *(const float2*)(np + (size_t)2 * NC);
                wB3 = *(const float2*)(np + (size_t)3 * NC);
            }
            int d = it * 4;
            const float* hp = &h_lds[d];
#pragma unroll
            for (int r = 0; r < 8; ++r) {
                float4 hv = *(const float4*)(hp + r * DSLICE);
                FMA_ROW2(acc[r], hv, wA0, wA1, wA2, wA3);
            }
            if (g1) {
#pragma unroll
                for (int r = 8; r < 16; ++r) {
                    float4 hv = *(const float4*)(hp + r * DSLICE);
                    FMA_ROW2(acc[r], hv, wA0, wA1, wA2, wA3);
                }
            }
            wp = np;
            wA0 = wB0; wA1 = wB1; wA2 = wB2; wA3 = wB3;
        }

        int cc = ct * CT2 + tid * 2;
#pragma unroll
        for (int r = 0; r < RB; ++r) {
            if (r < nrows) {
                int pos = e * 128 + rbase + r;
                float wgt = rowW[pos];
                int ri = rowIdx[pos];
                int kk = rowK[pos];
                float2 o = make_float2(wgt * acc[r].x, wgt * acc[r].y);
                *(float2*)&part[(((size_t)s * 128 + ri) * 2 + kk) * NC + cc] = o;
            }
        }
    }
}

// ---------------- K5: sum partials (unroll-4 MLP) + weighted bias, row softmax
__global__ __launch_bounds__(256) void k5_softmax(
    const float* __restrict__ part, const float* __restrict__ eb,
    const int* __restrict__ top2e, const float* __restrict__ top2w,
    float* __restrict__ out)
{
    int b = blockIdx.x;
    int tid = threadIdx.x;
    __shared__ float red[4];

    int e0 = top2e[b * 2], e1 = top2e[b * 2 + 1];
    float tw0 = top2w[b * 2], tw1 = top2w[b * 2 + 1];

    bool act = (tid < 250);
    int c0 = tid * 4;
    float4 v = make_float4(-1e30f, -1e30f, -1e30f, -1e30f);
    if (act) {
        float4 a0 = make_float4(0.f, 0.f, 0.f, 0.f);
        float4 a1 = a0, a2 = a0, a3 = a0;
        for (int s = 0; s < S4; s += 4) {
            const float* p0 = part + (((size_t)(s + 0) * 128 + b) * 2) * NC + c0;
            const float* p1 = part + (((size_t)(s + 1) * 128 + b) * 2) * NC + c0;
            const float* p2 = part + (((size_t)(s + 2) * 128 + b) * 2) * NC + c0;
            const float* p3 = part + (((size_t)(s + 3) * 128 + b) * 2) * NC + c0;
            float4 q00 = *(const float4*)p0;
            float4 q01 = *(const float4*)(p0 + NC);
            float4 q10 = *(const float4*)p1;
            float4 q11 = *(const float4*)(p1 + NC);
            float4 q20 = *(const float4*)p2;
            float4 q21 = *(const float4*)(p2 + NC);
            float4 q30 = *(const float4*)p3;
            float4 q31 = *(const float4*)(p3 + NC);
            a0.x += q00.x + q01.x; a0.y += q00.y + q01.y;
            a0.z += q00.z + q01.z; a0.w += q00.w + q01.w;
            a1.x += q10.x + q11.x; a1.y += q10.y + q11.y;
            a1.z += q10.z + q11.z; a1.w += q10.w + q11.w;
            a2.x += q20.x + q21.x; a2.y += q20.y + q21.y;
            a2.z += q20.z + q21.z; a2.w += q20.w + q21.w;
            a3.x += q30.x + q31.x; a3.y += q30.y + q31.y;
            a3.z += q30.z + q31.z; a3.w += q30.w + q31.w;
        }
        float4 a = make_float4(a0.x + a1.x + a2.x + a3.x,
                               a0.y + a1.y + a2.y + a3.y,
                               a0.z + a1.z + a2.z + a3.z,
                               a0.w + a1.w + a2.w + a3.w);
        float4 b0 = *(const float4*)(eb + e0 * NC + c0);
        float4 b1 = *(const float4*)(eb + e1 * NC + c0);
        v.x = a.x + tw0 * b0.x + tw1 * b1.x;
        v.y = a.y + tw0 * b0.y + tw1 * b1.y;
        v.z = a.z + tw0 * b0.z + tw1 * b1.z;
        v.w = a.w + tw0 * b0.w + tw1 * b1.w;
    }

    float m = fmaxf(fmaxf(v.x, v.y), fmaxf(v.z, v.w));
#pragma unroll
    for (int off = 32; off >= 1; off >>= 1)
        m = fmaxf(m, __shfl_xor(m, off, 64));
    int wid = tid >> 6, ln = tid & 63;
    if (ln == 0) red[wid] = m;
    __syncthreads();
    m = fmaxf(fmaxf(red[0], red[1]), fmaxf(red[2], red[3]));
    __syncthreads();

    float ex, ey, ez, ew2;
    ex = act ? expf(v.x - m) : 0.f;
    ey = act ? expf(v.y - m) : 0.f;
    ez = act ? expf(v.z - m) : 0.f;
    ew2 = act ? expf(v.w - m) : 0.f;
    float ssum = ex + ey + ez + ew2;
#pragma unroll
    for (int off = 32; off >= 1; off >>= 1)
        ssum += __shfl_xor(ssum, off, 64);
    if (ln == 0) red[wid] = ssum;
    __syncthreads();
    ssum = red[0] + red[1] + red[2] + red[3];
    float inv = 1.f / ssum;

    if (act) {
        float4 o = make_float4(ex * inv, ey * inv, ez * inv, ew2 * inv);
        *(float4*)&out[(size_t)b * NC + c0] = o;
    }
}

extern "C" void kernel_launch(void* const* d_in, const int* in_sizes, int n_in,
                              void* d_out, int out_size, void* d_ws, size_t ws_size,
                              hipStream_t stream) {
    const float* x   = (const float*)d_in[0];
    const float* c1w = (const float*)d_in[1];
    const float* c1b = (const float*)d_in[2];
    const float* c2w = (const float*)d_in[3];
    const float* c2b = (const float*)d_in[4];
    const float* gw  = (const float*)d_in[5];
    const float* gb  = (const float*)d_in[6];
    const float* ew  = (const float*)d_in[7];
    const float* eb  = (const float*)d_in[8];
    float* out = (float*)d_out;

    char* ws = (char*)d_ws;
    // layout (part overlays dead h1 region):
    //   smalls:  0 .. 16384
    //   h:       16384 .. 6438912                  (6,422,528 B)
    //   h1:      6438912 .. 22183936               (15,745,024 B, dead after k2)
    //   part:    6438912 .. 39206912               (32,768,000 B, alive k4..k5)
    int*   cnt    = (int*)  (ws + 0);        //    32 B
    int*   rowIdx = (int*)  (ws + 64);       //  4096 B
    float* rowW   = (float*)(ws + 4160);     //  4096 B
    int*   rowK   = (int*)  (ws + 8256);     //  4096 B
    int*   top2e  = (int*)  (ws + 12352);    //  1024 B
    float* top2w  = (float*)(ws + 13376);    //  1024 B
    float* h      = (float*)(ws + 16384);
    float* h1     = (float*)(ws + 6438912);
    float* part   = (float*)(ws + 6438912);

    k1_conv1<<<128 * 31 * 4, 256, 0, stream>>>(x, c1w, c1b, h1, cnt);
    k2_conv2<<<128 * 14 * 2, 448, 0, stream>>>(h1, c2w, c2b, h);
    k3_gate<<<128, 256, 0, stream>>>(h, gw, gb, cnt, rowIdx, rowW, rowK, top2e, top2w);
    k4_expert<<<S4 * 2 * 8 * 8, 256, 0, stream>>>(h, ew, cnt, rowIdx, rowW, rowK, part);
    k5_softmax<<<128, 256, 0, stream>>>(part, eb, top2e, top2w, out);
}